// Round 13
// baseline (505.221 us; speedup 1.0000x reference)
//
#include <hip/hip_runtime.h>

#define D 64
#define SLOPE 0.2f
#define BN_EPS 1e-5f
#define BSHIFT 9                  // 512 nodes per bucket
#define BUCKET 512
#define CHUNK 8192                // edges per partition block
#define CAP 7168                  // per-bucket arena capacity (mean ~6122 + ~13 sigma)
#define COLCAP (CAP + 7 * BUCKET) // per-bucket colbuf region (8-padding worst case)

// bf16 pack (RNE)
static __device__ __forceinline__ unsigned pk_bf16(float fx, float fy) {
    unsigned bx = __float_as_uint(fx);
    unsigned by = __float_as_uint(fy);
    bx = (bx + 0x7fffu + ((bx >> 16) & 1u)) >> 16;
    by = (by + 0x7fffu + ((by >> 16) & 1u)) & 0xffff0000u;
    return bx | by;
}
static __device__ __forceinline__ float bf_lo(unsigned u) { return __uint_as_float(u << 16); }
static __device__ __forceinline__ float bf_hi(unsigned u) { return __uint_as_float(u & 0xffff0000u); }

// ---------------------------------------------------------------------------
// LDS radix-partition straight from edge list; bucket b owns arena[b*CAP ..),
// cursor pcur[b] (zeroed by memset).
__global__ __launch_bounds__(256) void k_part(const int* __restrict__ src,
                                              const int* __restrict__ dst,
                                              int* __restrict__ pcur,
                                              unsigned* __restrict__ arena, int E) {
    __shared__ unsigned stage[CHUNK];
    __shared__ unsigned char bktb[CHUNK];
    __shared__ int hist[256], lofs[256], gbase[256];
    const int t = threadIdx.x;
    const int e0 = blockIdx.x * CHUNK;
    const int cn = min(CHUNK, E - e0);

    hist[t] = 0;
    __syncthreads();
    for (int i = t; i < cn; i += 256)
        atomicAdd(&hist[dst[e0 + i] >> BSHIFT], 1);
    __syncthreads();
    const int v = hist[t];
    lofs[t] = v;
    __syncthreads();
    for (int off = 1; off < 256; off <<= 1) {
        int x = lofs[t];
        if (t >= off) x += lofs[t - off];
        __syncthreads();
        lofs[t] = x;
        __syncthreads();
    }
    const int excl = lofs[t] - v;
    __syncthreads();
    lofs[t] = excl;
    if (v > 0) gbase[t] = t * CAP + atomicAdd(&pcur[t], v);
    __syncthreads();
    for (int i = t; i < cn; i += 256) {
        const int dd = dst[e0 + i];
        const int b  = dd >> BSHIFT;
        const int p  = atomicAdd(&lofs[b], 1);
        stage[p] = ((unsigned)(dd & (BUCKET - 1)) << 23) | (unsigned)src[e0 + i];
        bktb[p]  = (unsigned char)b;
    }
    __syncthreads();
    for (int i = t; i < cn; i += 256) {
        const int b = bktb[i];
        const int startb = lofs[b] - hist[b];
        arena[gbase[b] + (i - startb)] = stage[i];
    }
}

// per-bucket CSR build (8-padded) into fixed colbuf region; block 0 zeroes dummy row
__global__ __launch_bounds__(512) void k_build(const unsigned* __restrict__ arena,
                                               const int* __restrict__ pcur,
                                               int* __restrict__ rp, int* __restrict__ pcnt,
                                               int* __restrict__ colbuf, float* __restrict__ dinv,
                                               unsigned* __restrict__ ybf, int N) {
    __shared__ int ncnt[512], sc[512], lcur[512];
    const int t = threadIdx.x;
    const int b = blockIdx.x;
    const int nbase  = b << BSHIFT;
    const int nlocal = min(BUCKET, N - nbase);
    const int count  = pcur[b];
    const unsigned* ab = arena + (size_t)b * CAP;
    const int colbase = b * COLCAP;

    if (b == 0 && t < 32) ybf[(size_t)N * 32 + t] = 0u;   // dummy zero row N

    ncnt[t] = 0;
    __syncthreads();
    for (int i = t; i < count; i += 512)
        atomicAdd(&ncnt[ab[i] >> 23], 1);
    __syncthreads();
    const int v = ncnt[t];
    const int p = (v + 7) & ~7;                    // pad to multiple of 8
    sc[t] = p;
    __syncthreads();
    for (int off = 1; off < 512; off <<= 1) {
        int x = sc[t];
        if (t >= off) x += sc[t - off];
        __syncthreads();
        sc[t] = x;
        __syncthreads();
    }
    const int excl = sc[t] - p;
    lcur[t] = colbase + excl;
    if (t < nlocal) {
        rp[nbase + t]   = colbase + excl;
        pcnt[nbase + t] = p;
        dinv[nbase + t] = rsqrtf((float)v + 1.0f);
    }
    __syncthreads();
    for (int i = t; i < count; i += 512) {
        const unsigned u = ab[i];
        const int pos = atomicAdd(&lcur[u >> 23], 1);
        colbuf[pos] = (int)(u & 0x7FFFFFu);
    }
    if (t < nlocal)
        for (int k = v; k < p; ++k) colbuf[colbase + excl + k] = N;   // dummy -> zero row
}

// ---------------------------------------------------------------------------
// gemm with folded BN affine: ybf[row] = pack_bf16(((sc*x+sh) @ W) * dinv[row])
// BF16IN=0: x is fp32 (layer 0); BF16IN=1: x is packed bf16 h (layers 1,2).
template <int BF16IN>
__global__ __launch_bounds__(256) void k_gemm(const void* __restrict__ xin,
                                              const float* __restrict__ W,
                                              const float* __restrict__ stats,
                                              const float* __restrict__ gamma,
                                              const float* __restrict__ beta,
                                              const float* __restrict__ dinv,
                                              unsigned* __restrict__ ybf,
                                              float invN, int N) {
    __shared__ float scs[D], shs[D];
    const int tid = threadIdx.x;
    if (tid < D) {
        float sc = 1.f, sh = 0.f;
        if (BF16IN) {                                 // affine fold only for l>0
            const float mu  = stats[tid] * invN;
            const float var = stats[D + tid] * invN - mu * mu;
            sc = gamma[tid] * rsqrtf(var + BN_EPS);
            sh = beta[tid] - mu * sc;
        }
        scs[tid] = sc; shs[tid] = sh;
    }
    __syncthreads();
    const int lane = tid & 63;
    const int wib  = tid >> 6;
    float Wreg[D];
    float bv = 0.f;
#pragma unroll
    for (int k = 0; k < D; ++k) {
        const float w = W[k * D + lane];
        Wreg[k] = scs[k] * w;
        bv = fmaf(shs[k], w, bv);
    }
    const int stride = gridDim.x * 4;
    for (int row = __builtin_amdgcn_readfirstlane(blockIdx.x * 4 + wib); row < N; row += stride) {
        float acc = 0.f;
        if (BF16IN) {
            const uint4* xr = (const uint4*)((const unsigned*)xin + (size_t)row * 32);
#pragma unroll
            for (int j = 0; j < 8; ++j) {
                const uint4 u = xr[j];
                acc = fmaf(bf_lo(u.x), Wreg[8 * j + 0], acc);
                acc = fmaf(bf_hi(u.x), Wreg[8 * j + 1], acc);
                acc = fmaf(bf_lo(u.y), Wreg[8 * j + 2], acc);
                acc = fmaf(bf_hi(u.y), Wreg[8 * j + 3], acc);
                acc = fmaf(bf_lo(u.z), Wreg[8 * j + 4], acc);
                acc = fmaf(bf_hi(u.z), Wreg[8 * j + 5], acc);
                acc = fmaf(bf_lo(u.w), Wreg[8 * j + 6], acc);
                acc = fmaf(bf_hi(u.w), Wreg[8 * j + 7], acc);
            }
        } else {
            const float4* xr = (const float4*)((const float*)xin + (size_t)row * D);
#pragma unroll
            for (int k4 = 0; k4 < 16; ++k4) {
                const float4 xv = xr[k4];
                acc = fmaf(xv.x, Wreg[4 * k4 + 0], acc);
                acc = fmaf(xv.y, Wreg[4 * k4 + 1], acc);
                acc = fmaf(xv.z, Wreg[4 * k4 + 2], acc);
                acc = fmaf(xv.w, Wreg[4 * k4 + 3], acc);
            }
        }
        const float r  = (acc + bv) * dinv[row];
        const float rn = __shfl_down(r, 1, 64);
        if (!(lane & 1))
            ybf[(size_t)row * 32 + (lane >> 1)] = pk_bf16(r, rn);
    }
}

// ---------------------------------------------------------------------------
// pull (R7 structure, at the measured random-gather ceiling):
// half-wave per node, 8 independent gather chains, 8-padded lists, natural order.
// h written packed bf16; stats computed pre-rounding.
__global__ __launch_bounds__(256) void k_pull(const int* __restrict__ rp,
                                              const int* __restrict__ pcnt,
                                              const int* __restrict__ colbuf,
                                              const unsigned* __restrict__ ybf,
                                              const float* __restrict__ dinv,
                                              const float* __restrict__ b,
                                              unsigned* __restrict__ hbf,
                                              float* __restrict__ stats, int N) {
    const int tid  = threadIdx.x;
    const int lane = tid & 63;
    const int t32  = lane & 31;
    const int hw   = lane >> 5;
    const int wv   = tid >> 6;
    const float b0 = b[2 * t32];
    const float b1 = b[2 * t32 + 1];
    float s1a = 0.f, s1b = 0.f, s2a = 0.f, s2b = 0.f;
    const int gw = blockIdx.x * 4 + wv;
    const int gstride = gridDim.x * 4;

    for (int pr = gw; 2 * pr < N; pr += gstride) {
        const int n  = 2 * pr + hw;
        const bool vn = n < N;
        const int st = vn ? rp[n]   : 0;
        const int pd = vn ? pcnt[n] : 0;

        float a[8][2];
#pragma unroll
        for (int c = 0; c < 8; ++c) { a[c][0] = 0.f; a[c][1] = 0.f; }
        {   // self term
            const unsigned u = vn ? ybf[(size_t)n * 32 + t32] : 0u;
            a[0][0] = bf_lo(u); a[0][1] = bf_hi(u);
        }
        for (int w0 = 0; w0 < pd; w0 += 32) {
            const int wn = min(pd - w0, 32);                 // multiple of 8
            const int ci = (t32 < wn) ? colbuf[st + w0 + t32] : 0;
            for (int j0 = 0; j0 < wn; j0 += 8) {
#pragma unroll
                for (int jj = 0; jj < 8; ++jj) {
                    const int idx = __shfl(ci, hw * 32 + j0 + jj, 64);
                    const unsigned u = ybf[(size_t)idx * 32 + t32];
                    a[jj][0] += bf_lo(u);
                    a[jj][1] += bf_hi(u);
                }
            }
        }
        const float v0 = ((a[0][0] + a[1][0]) + (a[2][0] + a[3][0])) +
                         ((a[4][0] + a[5][0]) + (a[6][0] + a[7][0]));
        const float v1 = ((a[0][1] + a[1][1]) + (a[2][1] + a[3][1])) +
                         ((a[4][1] + a[5][1]) + (a[6][1] + a[7][1]));
        if (vn) {
            const float di = dinv[n];
            float t0 = fmaf(di, v0, b0); t0 = t0 > 0.f ? t0 : SLOPE * t0;
            float t1 = fmaf(di, v1, b1); t1 = t1 > 0.f ? t1 : SLOPE * t1;
            hbf[(size_t)n * 32 + t32] = pk_bf16(t0, t1);
            s1a += t0; s2a += t0 * t0;
            s1b += t1; s2b += t1 * t1;
        }
    }

    __shared__ float l1[64], l2[64];
    if (tid < 64) { l1[tid] = 0.f; l2[tid] = 0.f; }
    __syncthreads();
    atomicAdd(&l1[2 * t32],     s1a);
    atomicAdd(&l1[2 * t32 + 1], s1b);
    atomicAdd(&l2[2 * t32],     s2a);
    atomicAdd(&l2[2 * t32 + 1], s2b);
    __syncthreads();
    if (tid < 64) {
        atomicAdd(&stats[tid],      l1[tid]);
        atomicAdd(&stats[64 + tid], l2[tid]);
    }
}

// ---------------------------------------------------------------------------
// out(fp32) = sc * h(bf16) + sh; thread handles 8 consecutive features
__global__ __launch_bounds__(256) void k_normalize(const unsigned* __restrict__ hbf,
                                                   const float* __restrict__ stats,
                                                   const float* __restrict__ gamma,
                                                   const float* __restrict__ beta,
                                                   float* __restrict__ out,
                                                   float invN, int total8) {
    const int gt = blockIdx.x * 256 + threadIdx.x;
    const int c0 = (gt * 8) & 63;
    float sc[8], sh[8];
#pragma unroll
    for (int k = 0; k < 8; ++k) {
        const int c = c0 + k;
        const float mu  = stats[c] * invN;
        const float var = stats[64 + c] * invN - mu * mu;
        sc[k] = gamma[c] * rsqrtf(var + BN_EPS);
        sh[k] = beta[c] - mu * sc[k];
    }
    const uint4* h4 = (const uint4*)hbf;
    float4* o4 = (float4*)out;
    for (int i = gt; i < total8; i += gridDim.x * 256) {
        const uint4 u = h4[i];
        float4 r0, r1;
        r0.x = fmaf(sc[0], bf_lo(u.x), sh[0]);
        r0.y = fmaf(sc[1], bf_hi(u.x), sh[1]);
        r0.z = fmaf(sc[2], bf_lo(u.y), sh[2]);
        r0.w = fmaf(sc[3], bf_hi(u.y), sh[3]);
        r1.x = fmaf(sc[4], bf_lo(u.z), sh[4]);
        r1.y = fmaf(sc[5], bf_hi(u.z), sh[5]);
        r1.z = fmaf(sc[6], bf_lo(u.w), sh[6]);
        r1.w = fmaf(sc[7], bf_hi(u.w), sh[7]);
        o4[2 * i]     = r0;
        o4[2 * i + 1] = r1;
    }
}

// ---------------------------------------------------------------------------
extern "C" void kernel_launch(void* const* d_in, const int* in_sizes, int n_in,
                              void* d_out, int out_size, void* d_ws, size_t ws_size,
                              hipStream_t stream) {
    const float* x0     = (const float*)d_in[0];
    const int*   ei     = (const int*)d_in[1];
    const float* Ws     = (const float*)d_in[2];
    const float* bs     = (const float*)d_in[3];
    const float* gammas = (const float*)d_in[4];
    const float* betas  = (const float*)d_in[5];

    const int N = in_sizes[0] / D;
    const int E = in_sizes[1] / 2;
    const int L = in_sizes[2] / (D * D);
    const int nchunks = (E + CHUNK - 1) / CHUNK;
    const int NB = (N + BUCKET - 1) >> BSHIFT;

    const int* srcp = ei;
    const int* dstp = ei + E;

    char* wsb = (char*)d_ws;
    size_t o = 0;
    auto alloc = [&](size_t elems) { size_t r = o; o += (elems + 255) & ~(size_t)255; return r; };
    const size_t o_pcur  = alloc(256);                         // int, zeroed
    const size_t o_stats = alloc((size_t)L * 128);             // float, zeroed
    const size_t zero_end = o;
    const size_t o_rp    = alloc((size_t)N);                   // int
    const size_t o_pcnt  = alloc((size_t)N);                   // int
    const size_t o_dinv  = alloc((size_t)N);                   // float
    const size_t o_arena = alloc((size_t)NB * CAP);            // uint (per-bucket slices)
    const size_t o_col   = alloc((size_t)NB * COLCAP);         // int (8-padded, per-bucket)
    const size_t o_y     = alloc(((size_t)N + 1) * 32);        // uint (bf16x2), +dummy row
    const size_t o_h     = alloc((size_t)N * 32);              // uint (bf16x2 h)

    int*      pcur  = (int*)(wsb + o_pcur * 4);
    float*    stats = (float*)(wsb + o_stats * 4);
    int*      rp    = (int*)(wsb + o_rp * 4);
    int*      pcnt  = (int*)(wsb + o_pcnt * 4);
    float*    dinv  = (float*)(wsb + o_dinv * 4);
    unsigned* arena = (unsigned*)(wsb + o_arena * 4);
    int*      col   = (int*)(wsb + o_col * 4);
    unsigned* ybf   = (unsigned*)(wsb + o_y * 4);
    unsigned* hbf   = (unsigned*)(wsb + o_h * 4);
    float*    out   = (float*)d_out;

    hipMemsetAsync(d_ws, 0, zero_end * 4, stream);

    k_part <<<nchunks, 256, 0, stream>>>(srcp, dstp, pcur, arena, E);
    k_build<<<NB, 512, 0, stream>>>(arena, pcur, rp, pcnt, col, dinv, ybf, N);

    const float invN = 1.0f / (float)N;
    for (int l = 0; l < L; ++l) {
        const int pl = l ? l - 1 : 0;
        if (l == 0)
            k_gemm<0><<<1024, 256, 0, stream>>>(x0, Ws, stats, gammas, betas,
                                                dinv, ybf, invN, N);
        else
            k_gemm<1><<<1024, 256, 0, stream>>>(hbf, Ws + (size_t)l * D * D,
                                                stats + (size_t)pl * 128,
                                                gammas + (size_t)pl * D, betas + (size_t)pl * D,
                                                dinv, ybf, invN, N);
        k_pull<<<4096, 256, 0, stream>>>(rp, pcnt, col, ybf, dinv,
                                         bs + (size_t)l * D, hbf,
                                         stats + (size_t)l * 128, N);
    }
    k_normalize<<<1024, 256, 0, stream>>>(hbf, stats + (size_t)(L - 1) * 128,
                                          gammas + (size_t)(L - 1) * D,
                                          betas + (size_t)(L - 1) * D,
                                          out, invN, N * D / 8);
}

// Round 14
// 391.195 us; speedup vs baseline: 1.2915x; 1.2915x over previous
//
#include <hip/hip_runtime.h>

#define D 64
#define SLOPE 0.2f
#define BN_EPS 1e-5f
#define BSHIFT 9                  // 512 nodes per bucket
#define BUCKET 512
#define CHUNK 8192                // edges per partition block
#define CAP 7168                  // per-bucket arena capacity (mean ~6122 + ~13 sigma)
#define COLCAP (CAP + 7 * BUCKET) // per-bucket colbuf region (8-padding worst case)

// bf16 pack (RNE)
static __device__ __forceinline__ unsigned pk_bf16(float fx, float fy) {
    unsigned bx = __float_as_uint(fx);
    unsigned by = __float_as_uint(fy);
    bx = (bx + 0x7fffu + ((bx >> 16) & 1u)) >> 16;
    by = (by + 0x7fffu + ((by >> 16) & 1u)) & 0xffff0000u;
    return bx | by;
}
static __device__ __forceinline__ float bf_lo(unsigned u) { return __uint_as_float(u << 16); }
static __device__ __forceinline__ float bf_hi(unsigned u) { return __uint_as_float(u & 0xffff0000u); }

// ---------------------------------------------------------------------------
// LDS radix-partition straight from edge list; bucket b owns arena[b*CAP ..),
// cursor pcur[b] (zeroed by memset).
__global__ __launch_bounds__(256) void k_part(const int* __restrict__ src,
                                              const int* __restrict__ dst,
                                              int* __restrict__ pcur,
                                              unsigned* __restrict__ arena, int E) {
    __shared__ unsigned stage[CHUNK];
    __shared__ unsigned char bktb[CHUNK];
    __shared__ int hist[256], lofs[256], gbase[256];
    const int t = threadIdx.x;
    const int e0 = blockIdx.x * CHUNK;
    const int cn = min(CHUNK, E - e0);

    hist[t] = 0;
    __syncthreads();
    for (int i = t; i < cn; i += 256)
        atomicAdd(&hist[dst[e0 + i] >> BSHIFT], 1);
    __syncthreads();
    const int v = hist[t];
    lofs[t] = v;
    __syncthreads();
    for (int off = 1; off < 256; off <<= 1) {
        int x = lofs[t];
        if (t >= off) x += lofs[t - off];
        __syncthreads();
        lofs[t] = x;
        __syncthreads();
    }
    const int excl = lofs[t] - v;
    __syncthreads();
    lofs[t] = excl;
    if (v > 0) gbase[t] = t * CAP + atomicAdd(&pcur[t], v);
    __syncthreads();
    for (int i = t; i < cn; i += 256) {
        const int dd = dst[e0 + i];
        const int b  = dd >> BSHIFT;
        const int p  = atomicAdd(&lofs[b], 1);
        stage[p] = ((unsigned)(dd & (BUCKET - 1)) << 23) | (unsigned)src[e0 + i];
        bktb[p]  = (unsigned char)b;
    }
    __syncthreads();
    for (int i = t; i < cn; i += 256) {
        const int b = bktb[i];
        const int startb = lofs[b] - hist[b];
        arena[gbase[b] + (i - startb)] = stage[i];
    }
}

// per-bucket CSR build (8-padded) into fixed colbuf region; block 0 zeroes dummy row
__global__ __launch_bounds__(512) void k_build(const unsigned* __restrict__ arena,
                                               const int* __restrict__ pcur,
                                               int* __restrict__ rp, int* __restrict__ pcnt,
                                               int* __restrict__ colbuf, float* __restrict__ dinv,
                                               unsigned* __restrict__ ybf, int N) {
    __shared__ int ncnt[512], sc[512], lcur[512];
    const int t = threadIdx.x;
    const int b = blockIdx.x;
    const int nbase  = b << BSHIFT;
    const int nlocal = min(BUCKET, N - nbase);
    const int count  = pcur[b];
    const unsigned* ab = arena + (size_t)b * CAP;
    const int colbase = b * COLCAP;

    if (b == 0 && t < 32) ybf[(size_t)N * 32 + t] = 0u;   // dummy zero row N

    ncnt[t] = 0;
    __syncthreads();
    for (int i = t; i < count; i += 512)
        atomicAdd(&ncnt[ab[i] >> 23], 1);
    __syncthreads();
    const int v = ncnt[t];
    const int p = (v + 7) & ~7;                    // pad to multiple of 8
    sc[t] = p;
    __syncthreads();
    for (int off = 1; off < 512; off <<= 1) {
        int x = sc[t];
        if (t >= off) x += sc[t - off];
        __syncthreads();
        sc[t] = x;
        __syncthreads();
    }
    const int excl = sc[t] - p;
    lcur[t] = colbase + excl;
    if (t < nlocal) {
        rp[nbase + t]   = colbase + excl;
        pcnt[nbase + t] = p;
        dinv[nbase + t] = rsqrtf((float)v + 1.0f);
    }
    __syncthreads();
    for (int i = t; i < count; i += 512) {
        const unsigned u = ab[i];
        const int pos = atomicAdd(&lcur[u >> 23], 1);
        colbuf[pos] = (int)(u & 0x7FFFFFu);
    }
    if (t < nlocal)
        for (int k = v; k < p; ++k) colbuf[colbase + excl + k] = N;   // dummy -> zero row
}

// ---------------------------------------------------------------------------
// gemm with folded BN affine: ybf[row] = pack_bf16(((sc*x+sh) @ W) * dinv[row])
__global__ __launch_bounds__(256) void k_gemm(const float* __restrict__ x,
                                              const float* __restrict__ W,
                                              const float* __restrict__ stats,
                                              const float* __restrict__ gamma,
                                              const float* __restrict__ beta,
                                              const float* __restrict__ dinv,
                                              unsigned* __restrict__ ybf,
                                              float invN, int affine, int N) {
    __shared__ float scs[D], shs[D];
    const int tid = threadIdx.x;
    if (tid < D) {
        float sc = 1.f, sh = 0.f;
        if (affine) {
            const float mu  = stats[tid] * invN;
            const float var = stats[D + tid] * invN - mu * mu;
            sc = gamma[tid] * rsqrtf(var + BN_EPS);
            sh = beta[tid] - mu * sc;
        }
        scs[tid] = sc; shs[tid] = sh;
    }
    __syncthreads();
    const int lane = tid & 63;
    const int wib  = tid >> 6;
    float Wreg[D];
    float bv = 0.f;
#pragma unroll
    for (int k = 0; k < D; ++k) {
        const float w = W[k * D + lane];
        Wreg[k] = scs[k] * w;
        bv = fmaf(shs[k], w, bv);
    }
    const int stride = gridDim.x * 4;
    for (int row = __builtin_amdgcn_readfirstlane(blockIdx.x * 4 + wib); row < N; row += stride) {
        const float4* xr = (const float4*)(x + (size_t)row * D);
        float acc = 0.f;
#pragma unroll
        for (int k4 = 0; k4 < 16; ++k4) {
            const float4 xv = xr[k4];
            acc = fmaf(xv.x, Wreg[4 * k4 + 0], acc);
            acc = fmaf(xv.y, Wreg[4 * k4 + 1], acc);
            acc = fmaf(xv.z, Wreg[4 * k4 + 2], acc);
            acc = fmaf(xv.w, Wreg[4 * k4 + 3], acc);
        }
        const float r  = (acc + bv) * dinv[row];
        const float rn = __shfl_down(r, 1, 64);
        if (!(lane & 1))
            ybf[(size_t)row * 32 + (lane >> 1)] = pk_bf16(r, rn);
    }
}

// ---------------------------------------------------------------------------
// pull (R7 structure, at the measured random-gather ceiling ~2.0 TB/s):
// half-wave per node (32 lanes = full 64-feature row, 1 uint = 2 bf16 / lane),
// 8 independent gather chains, 8-padded edge lists -> branch-free inner body,
// natural node order (R10 lesson: do NOT permute; R13 lesson: grid 2048, fp32 h).
__global__ __launch_bounds__(256) void k_pull(const int* __restrict__ rp,
                                              const int* __restrict__ pcnt,
                                              const int* __restrict__ colbuf,
                                              const unsigned* __restrict__ ybf,
                                              const float* __restrict__ dinv,
                                              const float* __restrict__ b,
                                              float* __restrict__ h,
                                              float* __restrict__ stats, int N) {
    const int tid  = threadIdx.x;
    const int lane = tid & 63;
    const int t32  = lane & 31;
    const int hw   = lane >> 5;
    const int wv   = tid >> 6;
    const float b0 = b[2 * t32];
    const float b1 = b[2 * t32 + 1];
    float s1a = 0.f, s1b = 0.f, s2a = 0.f, s2b = 0.f;
    const int gw = blockIdx.x * 4 + wv;
    const int gstride = gridDim.x * 4;

    for (int pr = gw; 2 * pr < N; pr += gstride) {
        const int n  = 2 * pr + hw;
        const bool vn = n < N;
        const int st = vn ? rp[n]   : 0;
        const int pd = vn ? pcnt[n] : 0;

        float a[8][2];
#pragma unroll
        for (int c = 0; c < 8; ++c) { a[c][0] = 0.f; a[c][1] = 0.f; }
        {   // self term
            const unsigned u = vn ? ybf[(size_t)n * 32 + t32] : 0u;
            a[0][0] = bf_lo(u); a[0][1] = bf_hi(u);
        }
        for (int w0 = 0; w0 < pd; w0 += 32) {
            const int wn = min(pd - w0, 32);                 // multiple of 8
            const int ci = (t32 < wn) ? colbuf[st + w0 + t32] : 0;
            for (int j0 = 0; j0 < wn; j0 += 8) {
#pragma unroll
                for (int jj = 0; jj < 8; ++jj) {
                    const int idx = __shfl(ci, hw * 32 + j0 + jj, 64);
                    const unsigned u = ybf[(size_t)idx * 32 + t32];
                    a[jj][0] += bf_lo(u);
                    a[jj][1] += bf_hi(u);
                }
            }
        }
        const float v0 = ((a[0][0] + a[1][0]) + (a[2][0] + a[3][0])) +
                         ((a[4][0] + a[5][0]) + (a[6][0] + a[7][0]));
        const float v1 = ((a[0][1] + a[1][1]) + (a[2][1] + a[3][1])) +
                         ((a[4][1] + a[5][1]) + (a[6][1] + a[7][1]));
        if (vn) {
            const float di = dinv[n];
            float t0 = fmaf(di, v0, b0); t0 = t0 > 0.f ? t0 : SLOPE * t0;
            float t1 = fmaf(di, v1, b1); t1 = t1 > 0.f ? t1 : SLOPE * t1;
            *(float2*)&h[(size_t)n * D + 2 * t32] = make_float2(t0, t1);
            s1a += t0; s2a += t0 * t0;
            s1b += t1; s2b += t1 * t1;
        }
    }

    __shared__ float l1[64], l2[64];
    if (tid < 64) { l1[tid] = 0.f; l2[tid] = 0.f; }
    __syncthreads();
    atomicAdd(&l1[2 * t32],     s1a);
    atomicAdd(&l1[2 * t32 + 1], s1b);
    atomicAdd(&l2[2 * t32],     s2a);
    atomicAdd(&l2[2 * t32 + 1], s2b);
    __syncthreads();
    if (tid < 64) {
        atomicAdd(&stats[tid],      l1[tid]);
        atomicAdd(&stats[64 + tid], l2[tid]);
    }
}

// ---------------------------------------------------------------------------
__global__ __launch_bounds__(256) void k_normalize(const float* __restrict__ h,
                                                   const float* __restrict__ stats,
                                                   const float* __restrict__ gamma,
                                                   const float* __restrict__ beta,
                                                   float* __restrict__ out,
                                                   float invN, int total4) {
    const int gt = blockIdx.x * 256 + threadIdx.x;
    const int c0 = (gt * 4) & 63;
    float sc[4], sh[4];
#pragma unroll
    for (int k = 0; k < 4; ++k) {
        const int c = c0 + k;
        const float mu  = stats[c] * invN;
        const float var = stats[64 + c] * invN - mu * mu;
        sc[k] = gamma[c] * rsqrtf(var + BN_EPS);
        sh[k] = beta[c] - mu * sc[k];
    }
    const float4* h4 = (const float4*)h;
    float4* o4 = (float4*)out;
    for (int i = gt; i < total4; i += gridDim.x * 256) {
        float4 v = h4[i];
        v.x = fmaf(sc[0], v.x, sh[0]);
        v.y = fmaf(sc[1], v.y, sh[1]);
        v.z = fmaf(sc[2], v.z, sh[2]);
        v.w = fmaf(sc[3], v.w, sh[3]);
        o4[i] = v;
    }
}

// ---------------------------------------------------------------------------
extern "C" void kernel_launch(void* const* d_in, const int* in_sizes, int n_in,
                              void* d_out, int out_size, void* d_ws, size_t ws_size,
                              hipStream_t stream) {
    const float* x0     = (const float*)d_in[0];
    const int*   ei     = (const int*)d_in[1];
    const float* Ws     = (const float*)d_in[2];
    const float* bs     = (const float*)d_in[3];
    const float* gammas = (const float*)d_in[4];
    const float* betas  = (const float*)d_in[5];

    const int N = in_sizes[0] / D;
    const int E = in_sizes[1] / 2;
    const int L = in_sizes[2] / (D * D);
    const int nchunks = (E + CHUNK - 1) / CHUNK;
    const int NB = (N + BUCKET - 1) >> BSHIFT;

    const int* srcp = ei;
    const int* dstp = ei + E;

    char* wsb = (char*)d_ws;
    size_t o = 0;
    auto alloc = [&](size_t elems) { size_t r = o; o += (elems + 255) & ~(size_t)255; return r; };
    const size_t o_pcur  = alloc(256);                         // int, zeroed
    const size_t o_stats = alloc((size_t)L * 128);             // float, zeroed
    const size_t zero_end = o;
    const size_t o_rp    = alloc((size_t)N);                   // int
    const size_t o_pcnt  = alloc((size_t)N);                   // int
    const size_t o_dinv  = alloc((size_t)N);                   // float
    const size_t o_arena = alloc((size_t)NB * CAP);            // uint (per-bucket slices)
    const size_t o_col   = alloc((size_t)NB * COLCAP);         // int (8-padded, per-bucket)
    const size_t o_y     = alloc(((size_t)N + 1) * 32);        // uint (bf16x2), +dummy row

    int*      pcur  = (int*)(wsb + o_pcur * 4);
    float*    stats = (float*)(wsb + o_stats * 4);
    int*      rp    = (int*)(wsb + o_rp * 4);
    int*      pcnt  = (int*)(wsb + o_pcnt * 4);
    float*    dinv  = (float*)(wsb + o_dinv * 4);
    unsigned* arena = (unsigned*)(wsb + o_arena * 4);
    int*      col   = (int*)(wsb + o_col * 4);
    unsigned* ybf   = (unsigned*)(wsb + o_y * 4);
    float*    out   = (float*)d_out;
    float*    h     = out;                          // h shares d_out (fully rewritten)

    hipMemsetAsync(d_ws, 0, zero_end * 4, stream);

    k_part <<<nchunks, 256, 0, stream>>>(srcp, dstp, pcur, arena, E);
    k_build<<<NB, 512, 0, stream>>>(arena, pcur, rp, pcnt, col, dinv, ybf, N);

    const float invN = 1.0f / (float)N;
    const float* xin = x0;
    for (int l = 0; l < L; ++l) {
        const int pl = l ? l - 1 : 0;
        k_gemm<<<1024, 256, 0, stream>>>(xin, Ws + (size_t)l * D * D,
                                         stats + (size_t)pl * 128,
                                         gammas + (size_t)pl * D, betas + (size_t)pl * D,
                                         dinv, ybf, invN, l > 0 ? 1 : 0, N);
        k_pull<<<2048, 256, 0, stream>>>(rp, pcnt, col, ybf, dinv,
                                         bs + (size_t)l * D, h,
                                         stats + (size_t)l * 128, N);
        xin = h;
    }
    k_normalize<<<1024, 256, 0, stream>>>(h, stats + (size_t)(L - 1) * 128,
                                          gammas + (size_t)(L - 1) * D,
                                          betas + (size_t)(L - 1) * D,
                                          out, invN, N * D / 4);
}